// Round 1
// baseline (824.625 us; speedup 1.0000x reference)
//
#include <hip/hip_runtime.h>
#include <hip/hip_bf16.h>

#define NODELEN 394
#define IN_DIM 788
#define H2DIM 192
#define EMBDIM 128

// ---------------- CSR build ----------------

__global__ void count_deg(const int* __restrict__ dst, int* __restrict__ deg, int e) {
    int i = blockIdx.x * blockDim.x + threadIdx.x;
    if (i < e) atomicAdd(&deg[dst[i]], 1);
}

__global__ void block_sum(const int* __restrict__ deg, int* __restrict__ bsum, int n) {
    __shared__ int s[256];
    int t = threadIdx.x;
    int i = blockIdx.x * 256 + t;
    s[t] = (i < n) ? deg[i] : 0;
    __syncthreads();
    for (int d = 128; d > 0; d >>= 1) {
        if (t < d) s[t] += s[t + d];
        __syncthreads();
    }
    if (t == 0) bsum[blockIdx.x] = s[0];
}

// single block: exclusive-scan the block sums in place (nb <= 256)
__global__ void scan_bsums(int* bsum, int nb) {
    __shared__ int s[256];
    int t = threadIdx.x;
    int x0 = (t < nb) ? bsum[t] : 0;
    s[t] = x0;
    __syncthreads();
    for (int d = 1; d < 256; d <<= 1) {
        int u = (t >= d) ? s[t - d] : 0;
        __syncthreads();
        s[t] += u;
        __syncthreads();
    }
    if (t < nb) bsum[t] = s[t] - x0;  // exclusive offset of block t
}

__global__ void block_scan(const int* __restrict__ deg, const int* __restrict__ boff,
                           int* __restrict__ rowstart, int* __restrict__ cursor, int n) {
    __shared__ int s[256];
    int t = threadIdx.x;
    int i = blockIdx.x * 256 + t;
    int x0 = (i < n) ? deg[i] : 0;
    s[t] = x0;
    __syncthreads();
    for (int d = 1; d < 256; d <<= 1) {
        int u = (t >= d) ? s[t - d] : 0;
        __syncthreads();
        s[t] += u;
        __syncthreads();
    }
    if (i < n) {
        int r = boff[blockIdx.x] + s[t] - x0;  // exclusive prefix
        rowstart[i] = r;
        cursor[i] = r;
    }
}

__global__ void inv_deg_k(const int* __restrict__ deg, float* __restrict__ inv, int n) {
    int i = blockIdx.x * blockDim.x + threadIdx.x;
    if (i < n) inv[i] = 1.0f / fmaxf((float)deg[i], 1.0f);
}

__global__ void fill_edges(const int* __restrict__ src, const int* __restrict__ dst,
                           int* __restrict__ cursor, int* __restrict__ elist, int e) {
    int i = blockIdx.x * blockDim.x + threadIdx.x;
    if (i < e) {
        int p = atomicAdd(&cursor[dst[i]], 1);
        elist[p] = src[i];
    }
}

// ---------------- aggregation (gather) ----------------

// h1[node][f] = (f==0) ? 0 : mean over neighbors of features[nb][f]
__global__ void gather1(const float* __restrict__ feat, const int* __restrict__ rowstart,
                        const int* __restrict__ deg, const float* __restrict__ inv,
                        const int* __restrict__ elist, float* __restrict__ h1) {
    int node = blockIdx.x;
    int beg = rowstart[node];
    int dc = deg[node];
    float s = inv[node];
    float* out = h1 + (size_t)node * NODELEN;
    for (int f = threadIdx.x; f < NODELEN; f += blockDim.x) {
        float sum = 0.f;
        for (int j = 0; j < dc; ++j) {
            int nb = elist[beg + j];
            sum += feat[(size_t)nb * NODELEN + f];
        }
        out[f] = (f == 0) ? 0.f : sum * s;
    }
}

// emb[node][0:394]  = features (col0 zeroed)
// emb[node][394:788] = h2 = mean over neighbors of h1[nb][:] (col 394 zeroed)
__global__ void gather2_emb(const float* __restrict__ feat, const float* __restrict__ h1,
                            const int* __restrict__ rowstart, const int* __restrict__ deg,
                            const float* __restrict__ inv, const int* __restrict__ elist,
                            float* __restrict__ emb) {
    int node = blockIdx.x;
    int beg = rowstart[node];
    int dc = deg[node];
    float s = inv[node];
    const float* fr = feat + (size_t)node * NODELEN;
    float* er = emb + (size_t)node * IN_DIM;
    for (int f = threadIdx.x; f < NODELEN; f += blockDim.x) {
        er[f] = (f == 0) ? 0.f : fr[f];
        float sum = 0.f;
        for (int j = 0; j < dc; ++j) {
            int nb = elist[beg + j];
            sum += h1[(size_t)nb * NODELEN + f];
        }
        er[NODELEN + f] = (f == 0) ? 0.f : sum * s;
    }
}

// ---------------- fp32 tiled GEMM: C[M,N] = act(A[M,K] @ W[K,N] + b) ----------------

#define BM 128
#define BN 64
#define BK 32

template <int RELU>
__global__ __launch_bounds__(256) void gemm_bias(const float* __restrict__ A,
                                                 const float* __restrict__ W,
                                                 const float* __restrict__ bias,
                                                 float* __restrict__ C,
                                                 int M, int N, int K) {
    __shared__ float At[BK][BM + 4];  // [k][m], pad to 132 floats/row
    __shared__ float Ws[BK][BN + 4];  // [k][n], pad to 68

    int l = threadIdx.x;
    int m0 = blockIdx.x * BM;
    int n0 = blockIdx.y * BN;
    int tx = l & 15;   // 16 cols of 4
    int ty = l >> 4;   // 16 rows of 8
    float acc[8][4] = {};

    for (int k0 = 0; k0 < K; k0 += BK) {
        // stage A tile (128x32) as float4, store transposed
        #pragma unroll
        for (int i = 0; i < 4; ++i) {
            int idx = l + i * 256;       // float4 index
            int row = idx >> 3;          // 0..127
            int kc  = (idx & 7) << 2;    // 0,4,...,28
            float4 v = make_float4(0.f, 0.f, 0.f, 0.f);
            int gm = m0 + row, gk = k0 + kc;
            if (gm < M && gk < K)  // K % 4 == 0 for all our shapes
                v = *(const float4*)(A + (size_t)gm * K + gk);
            At[kc + 0][row] = v.x;
            At[kc + 1][row] = v.y;
            At[kc + 2][row] = v.z;
            At[kc + 3][row] = v.w;
        }
        // stage W tile (32x64) as float4
        #pragma unroll
        for (int i = 0; i < 2; ++i) {
            int idx = l + i * 256;
            int r = idx >> 4;            // 0..31
            int c = (idx & 15) << 2;     // 0..60
            float4 v = make_float4(0.f, 0.f, 0.f, 0.f);
            int gk = k0 + r, gn = n0 + c;
            if (gk < K && gn < N)  // N % 4 == 0 for all our shapes
                v = *(const float4*)(W + (size_t)gk * N + gn);
            *(float4*)&Ws[r][c] = v;
        }
        __syncthreads();

        #pragma unroll 8
        for (int k = 0; k < BK; ++k) {
            float a[8], w[4];
            #pragma unroll
            for (int i = 0; i < 8; ++i) a[i] = At[k][ty * 8 + i];
            #pragma unroll
            for (int j = 0; j < 4; ++j) w[j] = Ws[k][tx * 4 + j];
            #pragma unroll
            for (int i = 0; i < 8; ++i)
                #pragma unroll
                for (int j = 0; j < 4; ++j)
                    acc[i][j] += a[i] * w[j];
        }
        __syncthreads();
    }

    #pragma unroll
    for (int i = 0; i < 8; ++i) {
        int gm = m0 + ty * 8 + i;
        if (gm >= M) continue;
        #pragma unroll
        for (int j = 0; j < 4; ++j) {
            int gn = n0 + tx * 4 + j;
            if (gn >= N) continue;
            float v = acc[i][j] + bias[gn];
            if (RELU) v = fmaxf(v, 0.f);
            C[(size_t)gm * N + gn] = v;
        }
    }
}

// ---------------- launch ----------------

extern "C" void kernel_launch(void* const* d_in, const int* in_sizes, int n_in,
                              void* d_out, int out_size, void* d_ws, size_t ws_size,
                              hipStream_t stream) {
    const float* features = (const float*)d_in[0];
    const int*   src      = (const int*)d_in[1];
    const int*   dst      = (const int*)d_in[2];
    const float* W_enc1   = (const float*)d_in[3];
    const float* b_enc1   = (const float*)d_in[4];
    const float* W_enc3   = (const float*)d_in[5];
    const float* b_enc3   = (const float*)d_in[6];
    const float* W_dec1   = (const float*)d_in[7];
    const float* b_dec1   = (const float*)d_in[8];
    const float* W_dec3   = (const float*)d_in[9];
    const float* b_dec3   = (const float*)d_in[10];

    const int n = in_sizes[0] / NODELEN;  // 50000
    const int e = in_sizes[1];            // 200000

    // d_out layout: encoded [n,128] | decoded [n,788] | emb [n,788]
    float* encoded = (float*)d_out;
    float* decoded = encoded + (size_t)n * EMBDIM;
    float* emb     = decoded + (size_t)n * IN_DIM;

    // ws layout (bytes)
    char* ws = (char*)d_ws;
    float* h1       = (float*)(ws + 0);                    // n*394*4 = 78.8 MB
    float* x_buf    = (float*)(ws + 0);                    // n*192*4 (reuses h1 after hop-2)
    float* y_buf    = (float*)(ws + 38400000);             // n*192*4 (still inside h1 region)
    float* inv      = (float*)(ws + 78800000);             // n*4
    int*   deg      = (int*)  (ws + 79000000);             // n*4
    int*   rowstart = (int*)  (ws + 79200000);             // n*4
    int*   cursor   = (int*)  (ws + 79400000);             // n*4
    int*   elist    = (int*)  (ws + 79600000);             // e*4
    int*   bsum     = (int*)  (ws + 80400000);             // 196*4

    const int nb = (n + 255) / 256;   // 196 scan blocks (must be <= 256)
    const int eb = (e + 255) / 256;

    hipMemsetAsync(deg, 0, (size_t)n * sizeof(int), stream);
    count_deg<<<eb, 256, 0, stream>>>(dst, deg, e);
    block_sum<<<nb, 256, 0, stream>>>(deg, bsum, n);
    scan_bsums<<<1, 256, 0, stream>>>(bsum, nb);
    block_scan<<<nb, 256, 0, stream>>>(deg, bsum, rowstart, cursor, n);
    inv_deg_k<<<nb, 256, 0, stream>>>(deg, inv, n);
    fill_edges<<<eb, 256, 0, stream>>>(src, dst, cursor, elist, e);

    gather1<<<n, 256, 0, stream>>>(features, rowstart, deg, inv, elist, h1);
    gather2_emb<<<n, 256, 0, stream>>>(features, h1, rowstart, deg, inv, elist, emb);

    // MLP: emb(788) -> relu 192 -> 128 -> relu 192 -> 788
    dim3 blk(256);
    dim3 g1((n + BM - 1) / BM, (H2DIM + BN - 1) / BN);
    gemm_bias<1><<<g1, blk, 0, stream>>>(emb, W_enc1, b_enc1, x_buf, n, H2DIM, IN_DIM);
    dim3 g2((n + BM - 1) / BM, (EMBDIM + BN - 1) / BN);
    gemm_bias<0><<<g2, blk, 0, stream>>>(x_buf, W_enc3, b_enc3, encoded, n, EMBDIM, H2DIM);
    dim3 g3((n + BM - 1) / BM, (H2DIM + BN - 1) / BN);
    gemm_bias<1><<<g3, blk, 0, stream>>>(encoded, W_dec1, b_dec1, y_buf, n, H2DIM, EMBDIM);
    dim3 g4((n + BM - 1) / BM, (IN_DIM + BN - 1) / BN);
    gemm_bias<0><<<g4, blk, 0, stream>>>(y_buf, W_dec3, b_dec3, decoded, n, IN_DIM, H2DIM);
}

// Round 2
// 479.067 us; speedup vs baseline: 1.7213x; 1.7213x over previous
//
#include <hip/hip_runtime.h>
#include <hip/hip_bf16.h>

#define NODELEN 394
#define IN_DIM 788
#define H2DIM 192
#define EMBDIM 128

typedef __attribute__((ext_vector_type(4))) float f32x4;
typedef __attribute__((ext_vector_type(8))) short bfrag;  // 8 bf16 = 4 VGPRs

static __device__ __forceinline__ unsigned short f2bf(float f) {
    union { float f; unsigned u; } v; v.f = f;
    unsigned r = v.u + 0x7FFFu + ((v.u >> 16) & 1u);  // round-to-nearest-even
    return (unsigned short)(r >> 16);
}
static __device__ __forceinline__ float bf2f(unsigned short h) {
    union { unsigned u; float f; } v; v.u = ((unsigned)h) << 16;
    return v.f;
}

// ---------------- CSR build ----------------

__global__ void count_deg(const int* __restrict__ dst, int* __restrict__ deg, int e) {
    int i = blockIdx.x * blockDim.x + threadIdx.x;
    if (i < e) atomicAdd(&deg[dst[i]], 1);
}

__global__ void block_sum(const int* __restrict__ deg, int* __restrict__ bsum, int n) {
    __shared__ int s[256];
    int t = threadIdx.x;
    int i = blockIdx.x * 256 + t;
    s[t] = (i < n) ? deg[i] : 0;
    __syncthreads();
    for (int d = 128; d > 0; d >>= 1) {
        if (t < d) s[t] += s[t + d];
        __syncthreads();
    }
    if (t == 0) bsum[blockIdx.x] = s[0];
}

__global__ void scan_bsums(int* bsum, int nb) {
    __shared__ int s[256];
    int t = threadIdx.x;
    int x0 = (t < nb) ? bsum[t] : 0;
    s[t] = x0;
    __syncthreads();
    for (int d = 1; d < 256; d <<= 1) {
        int u = (t >= d) ? s[t - d] : 0;
        __syncthreads();
        s[t] += u;
        __syncthreads();
    }
    if (t < nb) bsum[t] = s[t] - x0;
}

__global__ void block_scan(const int* __restrict__ deg, const int* __restrict__ boff,
                           int* __restrict__ rowstart, int* __restrict__ cursor, int n) {
    __shared__ int s[256];
    int t = threadIdx.x;
    int i = blockIdx.x * 256 + t;
    int x0 = (i < n) ? deg[i] : 0;
    s[t] = x0;
    __syncthreads();
    for (int d = 1; d < 256; d <<= 1) {
        int u = (t >= d) ? s[t - d] : 0;
        __syncthreads();
        s[t] += u;
        __syncthreads();
    }
    if (i < n) {
        int r = boff[blockIdx.x] + s[t] - x0;
        rowstart[i] = r;
        cursor[i] = r;
    }
}

__global__ void inv_deg_k(const int* __restrict__ deg, float* __restrict__ inv, int n) {
    int i = blockIdx.x * blockDim.x + threadIdx.x;
    if (i < n) inv[i] = 1.0f / fmaxf((float)deg[i], 1.0f);
}

__global__ void fill_edges(const int* __restrict__ src, const int* __restrict__ dst,
                           int* __restrict__ cursor, int* __restrict__ elist, int e) {
    int i = blockIdx.x * blockDim.x + threadIdx.x;
    if (i < e) {
        int p = atomicAdd(&cursor[dst[i]], 1);
        elist[p] = src[i];
    }
}

// ---------------- aggregation (gather) ----------------

// h1 (bf16)[node][f] = (f==0) ? 0 : mean over neighbors of features[nb][f]
__global__ void gather1(const float* __restrict__ feat, const int* __restrict__ rowstart,
                        const int* __restrict__ deg, const float* __restrict__ inv,
                        const int* __restrict__ elist, unsigned short* __restrict__ h1) {
    int node = blockIdx.x;
    int beg = rowstart[node];
    int dc = deg[node];
    float s = inv[node];
    unsigned short* out = h1 + (size_t)node * NODELEN;
    for (int f = threadIdx.x; f < NODELEN; f += blockDim.x) {
        float sum = 0.f;
        for (int j = 0; j < dc; ++j) {
            int nb = elist[beg + j];
            sum += feat[(size_t)nb * NODELEN + f];
        }
        out[f] = (f == 0) ? (unsigned short)0 : f2bf(sum * s);
    }
}

// emb fp32 [node][788]: [0:394]=features (col0=0), [394:788]=mean of h1 (col394=0)
__global__ void gather2_emb(const float* __restrict__ feat, const unsigned short* __restrict__ h1,
                            const int* __restrict__ rowstart, const int* __restrict__ deg,
                            const float* __restrict__ inv, const int* __restrict__ elist,
                            float* __restrict__ emb) {
    int node = blockIdx.x;
    int beg = rowstart[node];
    int dc = deg[node];
    float s = inv[node];
    const float* fr = feat + (size_t)node * NODELEN;
    float* er = emb + (size_t)node * IN_DIM;
    for (int f = threadIdx.x; f < NODELEN; f += blockDim.x) {
        er[f] = (f == 0) ? 0.f : fr[f];
        float sum = 0.f;
        for (int j = 0; j < dc; ++j) {
            int nb = elist[beg + j];
            sum += bf2f(h1[(size_t)nb * NODELEN + f]);
        }
        er[NODELEN + f] = (f == 0) ? 0.f : sum * s;
    }
}

// ---------------- weight pre-transpose: W[K][N] fp32 -> Wt[N][Kp] bf16 (K zero-padded)
__global__ void transpose_w(const float* __restrict__ W, unsigned short* __restrict__ Wt,
                            int K, int N, int Kp) {
    int idx = blockIdx.x * 256 + threadIdx.x;
    if (idx >= N * Kp) return;
    int nrow = idx / Kp, k = idx - nrow * Kp;
    Wt[idx] = (k < K) ? f2bf(W[(size_t)k * N + nrow]) : (unsigned short)0;
}

// ---------------- bf16 MFMA GEMM ----------------
// C[M,N] = act(A[M,K] @ Wt^T + bias)  with Wt stored [N][Kp] bf16.
// 256 threads = 4 waves in 2x2; wave tile (MF*16) x (NF*16); block tile 32MF x 32NF.
// LDS tiles stored [row][k] with 40-elem padded rows (80 B, 16B-aligned, bank-uniform).
template <int MF, int NF, int RELU, int A_F32, int OUTF, int OUTB>
__global__ __launch_bounds__(256) void gemm_mfma(
    const void* __restrict__ Aptr, const unsigned short* __restrict__ Wt,
    const float* __restrict__ bias, float* __restrict__ Cf,
    unsigned short* __restrict__ Cb, int M, int N, int K, int Ksteps)
{
    constexpr int BMr = 32 * MF;
    constexpr int BNr = 32 * NF;
    __shared__ unsigned short As[BMr][40];
    __shared__ unsigned short Bs[BNr][40];

    const int tid = threadIdx.x;
    const int wid = tid >> 6, l = tid & 63;
    const int wm = wid >> 1, wn = wid & 1;
    const int lr = l & 15, lk = l >> 4;
    const int m0 = blockIdx.x * BMr;
    const int n0 = blockIdx.y * BNr;
    const int Kp = Ksteps * 32;

    f32x4 acc[MF][NF];
    #pragma unroll
    for (int i = 0; i < MF; ++i)
        #pragma unroll
        for (int j = 0; j < NF; ++j)
            acc[i][j] = (f32x4){0.f, 0.f, 0.f, 0.f};

    float bv[NF];
    #pragma unroll
    for (int j = 0; j < NF; ++j) {
        int gn = n0 + wn * NF * 16 + j * 16 + lr;
        bv[j] = (gn < N) ? bias[gn] : 0.f;
    }

    for (int kt = 0; kt < Ksteps; ++kt) {
        int k0 = kt * 32;
        // ---- stage A tile (BMr x 32) ----
        if (A_F32) {
            const float* A = (const float*)Aptr;
            for (int a = tid; a < BMr * 4; a += 256) {
                int row = a >> 2, q = a & 3;
                int gm = m0 + row, gk = k0 + q * 8;
                float4 v0 = make_float4(0.f, 0.f, 0.f, 0.f);
                float4 v1 = make_float4(0.f, 0.f, 0.f, 0.f);
                if (gm < M) {
                    if (gk < K)     v0 = *(const float4*)(A + (size_t)gm * K + gk);
                    if (gk + 4 < K) v1 = *(const float4*)(A + (size_t)gm * K + gk + 4);
                }
                union { unsigned short u[8]; bfrag v; } pk;
                pk.u[0] = f2bf(v0.x); pk.u[1] = f2bf(v0.y);
                pk.u[2] = f2bf(v0.z); pk.u[3] = f2bf(v0.w);
                pk.u[4] = f2bf(v1.x); pk.u[5] = f2bf(v1.y);
                pk.u[6] = f2bf(v1.z); pk.u[7] = f2bf(v1.w);
                *(bfrag*)&As[row][q * 8] = pk.v;
            }
        } else {
            const unsigned short* A = (const unsigned short*)Aptr;
            for (int a = tid; a < BMr * 2; a += 256) {
                int row = a >> 1, h = a & 1;
                int gm = m0 + row;
                bfrag v0 = {0,0,0,0,0,0,0,0}, v1 = {0,0,0,0,0,0,0,0};
                if (gm < M) {
                    const unsigned short* p = A + (size_t)gm * K + k0 + h * 16;
                    v0 = *(const bfrag*)p;
                    v1 = *(const bfrag*)(p + 8);
                }
                *(bfrag*)&As[row][h * 16]     = v0;
                *(bfrag*)&As[row][h * 16 + 8] = v1;
            }
        }
        // ---- stage B tile (BNr x 32) from Wt[N][Kp] ----
        for (int a = tid; a < BNr * 2; a += 256) {
            int row = a >> 1, h = a & 1;
            int gn = n0 + row;
            bfrag v0 = {0,0,0,0,0,0,0,0}, v1 = {0,0,0,0,0,0,0,0};
            if (gn < N) {
                const unsigned short* p = Wt + (size_t)gn * Kp + k0 + h * 16;
                v0 = *(const bfrag*)p;
                v1 = *(const bfrag*)(p + 8);
            }
            *(bfrag*)&Bs[row][h * 16]     = v0;
            *(bfrag*)&Bs[row][h * 16 + 8] = v1;
        }
        __syncthreads();

        bfrag af[MF], bfr[NF];
        #pragma unroll
        for (int i = 0; i < MF; ++i)
            af[i] = *(const bfrag*)&As[wm * MF * 16 + i * 16 + lr][lk * 8];
        #pragma unroll
        for (int j = 0; j < NF; ++j)
            bfr[j] = *(const bfrag*)&Bs[wn * NF * 16 + j * 16 + lr][lk * 8];
        #pragma unroll
        for (int i = 0; i < MF; ++i)
            #pragma unroll
            for (int j = 0; j < NF; ++j)
                acc[i][j] = __builtin_amdgcn_mfma_f32_16x16x32_bf16(af[i], bfr[j], acc[i][j], 0, 0, 0);
        __syncthreads();
    }

    // epilogue: D row = (lane>>4)*4 + reg, col = lane&15  (m89-verified layout)
    #pragma unroll
    for (int i = 0; i < MF; ++i) {
        #pragma unroll
        for (int j = 0; j < NF; ++j) {
            #pragma unroll
            for (int r = 0; r < 4; ++r) {
                int gm = m0 + wm * MF * 16 + i * 16 + lk * 4 + r;
                int gn = n0 + wn * NF * 16 + j * 16 + lr;
                if (gm < M && gn < N) {
                    float v = acc[i][j][r] + bv[j];
                    if (RELU) v = fmaxf(v, 0.f);
                    if (OUTF) Cf[(size_t)gm * N + gn] = v;
                    if (OUTB) Cb[(size_t)gm * N + gn] = f2bf(v);
                }
            }
        }
    }
}

// ---------------- launch ----------------

extern "C" void kernel_launch(void* const* d_in, const int* in_sizes, int n_in,
                              void* d_out, int out_size, void* d_ws, size_t ws_size,
                              hipStream_t stream) {
    const float* features = (const float*)d_in[0];
    const int*   src      = (const int*)d_in[1];
    const int*   dst      = (const int*)d_in[2];
    const float* W_enc1   = (const float*)d_in[3];
    const float* b_enc1   = (const float*)d_in[4];
    const float* W_enc3   = (const float*)d_in[5];
    const float* b_enc3   = (const float*)d_in[6];
    const float* W_dec1   = (const float*)d_in[7];
    const float* b_dec1   = (const float*)d_in[8];
    const float* W_dec3   = (const float*)d_in[9];
    const float* b_dec3   = (const float*)d_in[10];

    const int n = in_sizes[0] / NODELEN;  // 50000
    const int e = in_sizes[1];            // 200000

    // d_out layout: encoded [n,128] | decoded [n,788] | emb [n,788]
    float* encoded = (float*)d_out;
    float* decoded = encoded + (size_t)n * EMBDIM;
    float* emb     = decoded + (size_t)n * IN_DIM;

    // ws layout (bytes); h1 region is reused for bf16 intermediates after gather2
    char* ws = (char*)d_ws;
    unsigned short* h1    = (unsigned short*)(ws + 0);         // n*394*2 = 39.4 MB
    unsigned short* x16   = (unsigned short*)(ws + 0);         // n*192*2 = 19.2 MB
    unsigned short* enc16 = (unsigned short*)(ws + 19200000);  // n*128*2 = 12.8 MB
    unsigned short* y16   = (unsigned short*)(ws + 32000000);  // n*192*2 = 19.2 MB
    unsigned short* Wt1   = (unsigned short*)(ws + 52000000);  // 192*800*2
    unsigned short* Wt2   = (unsigned short*)(ws + 52400000);  // 128*192*2
    unsigned short* Wt3   = (unsigned short*)(ws + 52500000);  // 192*128*2
    unsigned short* Wt4   = (unsigned short*)(ws + 52600000);  // 788*192*2
    float* inv            = (float*)(ws + 53000000);
    int*   deg            = (int*)  (ws + 53200000);
    int*   rowstart       = (int*)  (ws + 53400000);
    int*   cursor         = (int*)  (ws + 53600000);
    int*   elist          = (int*)  (ws + 53800000);           // e*4 = 800 KB
    int*   bsum           = (int*)  (ws + 54600000);

    const int nb = (n + 255) / 256;
    const int eb = (e + 255) / 256;

    // weight transposes (region untouched by h1) — can run up front
    transpose_w<<<(192 * 800 + 255) / 256, 256, 0, stream>>>(W_enc1, Wt1, IN_DIM, H2DIM, 800);
    transpose_w<<<(128 * 192 + 255) / 256, 256, 0, stream>>>(W_enc3, Wt2, H2DIM, EMBDIM, 192);
    transpose_w<<<(192 * 128 + 255) / 256, 256, 0, stream>>>(W_dec1, Wt3, EMBDIM, H2DIM, 128);
    transpose_w<<<(788 * 192 + 255) / 256, 256, 0, stream>>>(W_dec3, Wt4, H2DIM, IN_DIM, 192);

    hipMemsetAsync(deg, 0, (size_t)n * sizeof(int), stream);
    count_deg<<<eb, 256, 0, stream>>>(dst, deg, e);
    block_sum<<<nb, 256, 0, stream>>>(deg, bsum, n);
    scan_bsums<<<1, 256, 0, stream>>>(bsum, nb);
    block_scan<<<nb, 256, 0, stream>>>(deg, bsum, rowstart, cursor, n);
    inv_deg_k<<<nb, 256, 0, stream>>>(deg, inv, n);
    fill_edges<<<eb, 256, 0, stream>>>(src, dst, cursor, elist, e);

    gather1<<<n, 256, 0, stream>>>(features, rowstart, deg, inv, elist, h1);
    gather2_emb<<<n, 256, 0, stream>>>(features, h1, rowstart, deg, inv, elist, emb);

    // MLP via bf16 MFMA
    // gemm1: emb(f32)[n,788] @ W1 -> relu -> x16 (bf16). block 64x192 (full N), A read once.
    gemm_mfma<2, 6, 1, 1, 0, 1><<<dim3(782, 1), 256, 0, stream>>>(
        emb, Wt1, b_enc1, nullptr, x16, n, H2DIM, IN_DIM, 25);
    // gemm2: x16 @ W2 -> encoded (f32 out) + enc16 (bf16). block 128x128 (full N).
    gemm_mfma<4, 4, 0, 0, 1, 1><<<dim3(391, 1), 256, 0, stream>>>(
        x16, Wt2, b_enc3, encoded, enc16, n, EMBDIM, H2DIM, 6);
    // gemm3: enc16 @ W3 -> relu -> y16. block 64x192 (full N).
    gemm_mfma<2, 6, 1, 0, 0, 1><<<dim3(782, 1), 256, 0, stream>>>(
        enc16, Wt3, b_dec1, nullptr, y16, n, H2DIM, EMBDIM, 4);
    // gemm4: y16 @ W4 -> decoded (f32). block 128x128, 7 n-blocks.
    gemm_mfma<4, 4, 0, 0, 1, 0><<<dim3(391, 7), 256, 0, stream>>>(
        y16, Wt4, b_dec3, decoded, nullptr, n, IN_DIM, H2DIM, 6);
}

// Round 3
// 387.985 us; speedup vs baseline: 2.1254x; 1.2348x over previous
//
#include <hip/hip_runtime.h>
#include <hip/hip_bf16.h>

#define NODELEN 394
#define IN_DIM 788
#define H2DIM 192
#define EMBDIM 128
#define NCHUNK 197   // 394 elems = 197 x (float2 | uint-packed-bf16x2)

typedef __attribute__((ext_vector_type(4))) float f32x4;
typedef __attribute__((ext_vector_type(8))) short bfrag;  // 8 bf16 = 4 VGPRs

static __device__ __forceinline__ unsigned short f2bf(float f) {
    union { float f; unsigned u; } v; v.f = f;
    unsigned r = v.u + 0x7FFFu + ((v.u >> 16) & 1u);  // round-to-nearest-even
    return (unsigned short)(r >> 16);
}
static __device__ __forceinline__ float bf2f(unsigned short h) {
    union { unsigned u; float f; } v; v.u = ((unsigned)h) << 16;
    return v.f;
}

// ---------------- CSR build ----------------

__global__ void count_deg(const int* __restrict__ dst, int* __restrict__ deg, int e) {
    int i = blockIdx.x * blockDim.x + threadIdx.x;
    if (i < e) atomicAdd(&deg[dst[i]], 1);
}

__global__ void block_sum(const int* __restrict__ deg, int* __restrict__ bsum, int n) {
    __shared__ int s[256];
    int t = threadIdx.x;
    int i = blockIdx.x * 256 + t;
    s[t] = (i < n) ? deg[i] : 0;
    __syncthreads();
    for (int d = 128; d > 0; d >>= 1) {
        if (t < d) s[t] += s[t + d];
        __syncthreads();
    }
    if (t == 0) bsum[blockIdx.x] = s[0];
}

__global__ void scan_bsums(int* bsum, int nb) {
    __shared__ int s[256];
    int t = threadIdx.x;
    int x0 = (t < nb) ? bsum[t] : 0;
    s[t] = x0;
    __syncthreads();
    for (int d = 1; d < 256; d <<= 1) {
        int u = (t >= d) ? s[t - d] : 0;
        __syncthreads();
        s[t] += u;
        __syncthreads();
    }
    if (t < nb) bsum[t] = s[t] - x0;
}

__global__ void block_scan(const int* __restrict__ deg, const int* __restrict__ boff,
                           int* __restrict__ rowstart, int* __restrict__ cursor, int n) {
    __shared__ int s[256];
    int t = threadIdx.x;
    int i = blockIdx.x * 256 + t;
    int x0 = (i < n) ? deg[i] : 0;
    s[t] = x0;
    __syncthreads();
    for (int d = 1; d < 256; d <<= 1) {
        int u = (t >= d) ? s[t - d] : 0;
        __syncthreads();
        s[t] += u;
        __syncthreads();
    }
    if (i < n) {
        int r = boff[blockIdx.x] + s[t] - x0;
        rowstart[i] = r;
        cursor[i] = r;
    }
}

__global__ void inv_deg_k(const int* __restrict__ deg, float* __restrict__ inv, int n) {
    int i = blockIdx.x * blockDim.x + threadIdx.x;
    if (i < n) inv[i] = 1.0f / fmaxf((float)deg[i], 1.0f);
}

__global__ void fill_edges(const int* __restrict__ src, const int* __restrict__ dst,
                           int* __restrict__ cursor, int* __restrict__ elist, int e) {
    int i = blockIdx.x * blockDim.x + threadIdx.x;
    if (i < e) {
        int p = atomicAdd(&cursor[dst[i]], 1);
        elist[p] = src[i];
    }
}

// ---------------- aggregation (gather, float2-vectorized, 4-deep neighbor ILP) ----

// h1 (bf16)[node][f] = (f==0) ? 0 : mean over neighbors of features[nb][f]
__global__ __launch_bounds__(256) void gather1(
        const float* __restrict__ feat, const int* __restrict__ rowstart,
        const int* __restrict__ deg, const float* __restrict__ inv,
        const int* __restrict__ elist, unsigned short* __restrict__ h1) {
    const int node = blockIdx.x;
    const int c = threadIdx.x;          // float2 chunk id, 0..196
    if (c >= NCHUNK) return;
    const int beg = rowstart[node];
    const int dc = deg[node];
    const float s = inv[node];
    const size_t off = (size_t)c * 2;

    float ax = 0.f, ay = 0.f, bx = 0.f, by = 0.f;
    float cx = 0.f, cy = 0.f, dx = 0.f, dy = 0.f;
    int j = 0;
    for (; j + 3 < dc; j += 4) {
        int n0 = elist[beg + j], n1 = elist[beg + j + 1];
        int n2 = elist[beg + j + 2], n3 = elist[beg + j + 3];
        float2 v0 = *(const float2*)(feat + (size_t)n0 * NODELEN + off);
        float2 v1 = *(const float2*)(feat + (size_t)n1 * NODELEN + off);
        float2 v2 = *(const float2*)(feat + (size_t)n2 * NODELEN + off);
        float2 v3 = *(const float2*)(feat + (size_t)n3 * NODELEN + off);
        ax += v0.x; ay += v0.y; bx += v1.x; by += v1.y;
        cx += v2.x; cy += v2.y; dx += v3.x; dy += v3.y;
    }
    for (; j < dc; ++j) {
        int n0 = elist[beg + j];
        float2 v0 = *(const float2*)(feat + (size_t)n0 * NODELEN + off);
        ax += v0.x; ay += v0.y;
    }
    float fx = (ax + bx + cx + dx) * s;
    float fy = (ay + by + cy + dy) * s;
    if (c == 0) fx = 0.f;
    unsigned out = ((unsigned)f2bf(fy) << 16) | (unsigned)f2bf(fx);
    *(unsigned*)(h1 + (size_t)node * NODELEN + off) = out;
}

// emb fp32 [node][788]: [0:394]=features (col0=0), [394:788]=mean of h1 (col394=0)
__global__ __launch_bounds__(256) void gather2_emb(
        const float* __restrict__ feat, const unsigned* __restrict__ h1,
        const int* __restrict__ rowstart, const int* __restrict__ deg,
        const float* __restrict__ inv, const int* __restrict__ elist,
        float* __restrict__ emb) {
    const int node = blockIdx.x;
    const int c = threadIdx.x;          // chunk id, 0..196
    if (c >= NCHUNK) return;
    const int beg = rowstart[node];
    const int dc = deg[node];
    const float s = inv[node];
    const size_t h1row2 = (size_t)NODELEN / 2;  // not integral; use uint index math below

    // h1 row in uints: node*197 uints? row is 394 bf16 = 197 uints, contiguous rows
    // h1 as unsigned*: element (node, chunk c) at node*197 + c
    float ax = 0.f, ay = 0.f, bx = 0.f, by = 0.f;
    float cx = 0.f, cy = 0.f, dx = 0.f, dy = 0.f;
    int j = 0;
    for (; j + 3 < dc; j += 4) {
        int n0 = elist[beg + j], n1 = elist[beg + j + 1];
        int n2 = elist[beg + j + 2], n3 = elist[beg + j + 3];
        unsigned u0 = h1[(size_t)n0 * NCHUNK + c];
        unsigned u1 = h1[(size_t)n1 * NCHUNK + c];
        unsigned u2 = h1[(size_t)n2 * NCHUNK + c];
        unsigned u3 = h1[(size_t)n3 * NCHUNK + c];
        ax += bf2f((unsigned short)u0); ay += bf2f((unsigned short)(u0 >> 16));
        bx += bf2f((unsigned short)u1); by += bf2f((unsigned short)(u1 >> 16));
        cx += bf2f((unsigned short)u2); cy += bf2f((unsigned short)(u2 >> 16));
        dx += bf2f((unsigned short)u3); dy += bf2f((unsigned short)(u3 >> 16));
    }
    for (; j < dc; ++j) {
        int n0 = elist[beg + j];
        unsigned u0 = h1[(size_t)n0 * NCHUNK + c];
        ax += bf2f((unsigned short)u0); ay += bf2f((unsigned short)(u0 >> 16));
    }
    float hx = (ax + bx + cx + dx) * s;
    float hy = (ay + by + cy + dy) * s;

    const float* fr = feat + (size_t)node * NODELEN;
    float* er = emb + (size_t)node * IN_DIM;
    float2 fv = *(const float2*)(fr + c * 2);
    if (c == 0) { fv.x = 0.f; hx = 0.f; }
    *(float2*)(er + c * 2) = fv;
    float2 hv; hv.x = hx; hv.y = hy;
    *(float2*)(er + NODELEN + c * 2) = hv;
}

// ---------------- weight pre-transpose: W[K][N] fp32 -> Wt[N][Kp] bf16 (K zero-padded)
__global__ void transpose_w(const float* __restrict__ W, unsigned short* __restrict__ Wt,
                            int K, int N, int Kp) {
    int idx = blockIdx.x * 256 + threadIdx.x;
    if (idx >= N * Kp) return;
    int nrow = idx / Kp, k = idx - nrow * Kp;
    Wt[idx] = (k < K) ? f2bf(W[(size_t)k * N + nrow]) : (unsigned short)0;
}

// ---------------- bf16 MFMA GEMM ----------------
// C[M,N] = act(A[M,K] @ Wt^T + bias)  with Wt stored [N][Kp] bf16.
// 256 threads = 4 waves in 2x2; wave tile (MF*16) x (NF*16); block tile 32MF x 32NF.
// LDS tiles stored [row][k] with 40-elem padded rows (80 B, 16B-aligned, bank-uniform).
template <int MF, int NF, int RELU, int A_F32, int OUTF, int OUTB>
__global__ __launch_bounds__(256) void gemm_mfma(
    const void* __restrict__ Aptr, const unsigned short* __restrict__ Wt,
    const float* __restrict__ bias, float* __restrict__ Cf,
    unsigned short* __restrict__ Cb, int M, int N, int K, int Ksteps)
{
    constexpr int BMr = 32 * MF;
    constexpr int BNr = 32 * NF;
    __shared__ unsigned short As[BMr][40];
    __shared__ unsigned short Bs[BNr][40];

    const int tid = threadIdx.x;
    const int wid = tid >> 6, l = tid & 63;
    const int wm = wid >> 1, wn = wid & 1;
    const int lr = l & 15, lk = l >> 4;
    const int m0 = blockIdx.x * BMr;
    const int n0 = blockIdx.y * BNr;
    const int Kp = Ksteps * 32;

    f32x4 acc[MF][NF];
    #pragma unroll
    for (int i = 0; i < MF; ++i)
        #pragma unroll
        for (int j = 0; j < NF; ++j)
            acc[i][j] = (f32x4){0.f, 0.f, 0.f, 0.f};

    float bv[NF];
    #pragma unroll
    for (int j = 0; j < NF; ++j) {
        int gn = n0 + wn * NF * 16 + j * 16 + lr;
        bv[j] = (gn < N) ? bias[gn] : 0.f;
    }

    for (int kt = 0; kt < Ksteps; ++kt) {
        int k0 = kt * 32;
        // ---- stage A tile (BMr x 32) ----
        if (A_F32) {
            const float* A = (const float*)Aptr;
            for (int a = tid; a < BMr * 4; a += 256) {
                int row = a >> 2, q = a & 3;
                int gm = m0 + row, gk = k0 + q * 8;
                float4 v0 = make_float4(0.f, 0.f, 0.f, 0.f);
                float4 v1 = make_float4(0.f, 0.f, 0.f, 0.f);
                if (gm < M) {
                    if (gk < K)     v0 = *(const float4*)(A + (size_t)gm * K + gk);
                    if (gk + 4 < K) v1 = *(const float4*)(A + (size_t)gm * K + gk + 4);
                }
                union { unsigned short u[8]; bfrag v; } pk;
                pk.u[0] = f2bf(v0.x); pk.u[1] = f2bf(v0.y);
                pk.u[2] = f2bf(v0.z); pk.u[3] = f2bf(v0.w);
                pk.u[4] = f2bf(v1.x); pk.u[5] = f2bf(v1.y);
                pk.u[6] = f2bf(v1.z); pk.u[7] = f2bf(v1.w);
                *(bfrag*)&As[row][q * 8] = pk.v;
            }
        } else {
            const unsigned short* A = (const unsigned short*)Aptr;
            for (int a = tid; a < BMr * 2; a += 256) {
                int row = a >> 1, h = a & 1;
                int gm = m0 + row;
                bfrag v0 = {0,0,0,0,0,0,0,0}, v1 = {0,0,0,0,0,0,0,0};
                if (gm < M) {
                    const unsigned short* p = A + (size_t)gm * K + k0 + h * 16;
                    v0 = *(const bfrag*)p;
                    v1 = *(const bfrag*)(p + 8);
                }
                *(bfrag*)&As[row][h * 16]     = v0;
                *(bfrag*)&As[row][h * 16 + 8] = v1;
            }
        }
        // ---- stage B tile (BNr x 32) from Wt[N][Kp] ----
        for (int a = tid; a < BNr * 2; a += 256) {
            int row = a >> 1, h = a & 1;
            int gn = n0 + row;
            bfrag v0 = {0,0,0,0,0,0,0,0}, v1 = {0,0,0,0,0,0,0,0};
            if (gn < N) {
                const unsigned short* p = Wt + (size_t)gn * Kp + k0 + h * 16;
                v0 = *(const bfrag*)p;
                v1 = *(const bfrag*)(p + 8);
            }
            *(bfrag*)&Bs[row][h * 16]     = v0;
            *(bfrag*)&Bs[row][h * 16 + 8] = v1;
        }
        __syncthreads();

        bfrag af[MF], bfr[NF];
        #pragma unroll
        for (int i = 0; i < MF; ++i)
            af[i] = *(const bfrag*)&As[wm * MF * 16 + i * 16 + lr][lk * 8];
        #pragma unroll
        for (int j = 0; j < NF; ++j)
            bfr[j] = *(const bfrag*)&Bs[wn * NF * 16 + j * 16 + lr][lk * 8];
        #pragma unroll
        for (int i = 0; i < MF; ++i)
            #pragma unroll
            for (int j = 0; j < NF; ++j)
                acc[i][j] = __builtin_amdgcn_mfma_f32_16x16x32_bf16(af[i], bfr[j], acc[i][j], 0, 0, 0);
        __syncthreads();
    }

    // epilogue: D row = (lane>>4)*4 + reg, col = lane&15  (m89-verified layout)
    #pragma unroll
    for (int i = 0; i < MF; ++i) {
        #pragma unroll
        for (int j = 0; j < NF; ++j) {
            #pragma unroll
            for (int r = 0; r < 4; ++r) {
                int gm = m0 + wm * MF * 16 + i * 16 + lk * 4 + r;
                int gn = n0 + wn * NF * 16 + j * 16 + lr;
                if (gm < M && gn < N) {
                    float v = acc[i][j][r] + bv[j];
                    if (RELU) v = fmaxf(v, 0.f);
                    if (OUTF) Cf[(size_t)gm * N + gn] = v;
                    if (OUTB) Cb[(size_t)gm * N + gn] = f2bf(v);
                }
            }
        }
    }
}

// ---------------- launch ----------------

extern "C" void kernel_launch(void* const* d_in, const int* in_sizes, int n_in,
                              void* d_out, int out_size, void* d_ws, size_t ws_size,
                              hipStream_t stream) {
    const float* features = (const float*)d_in[0];
    const int*   src      = (const int*)d_in[1];
    const int*   dst      = (const int*)d_in[2];
    const float* W_enc1   = (const float*)d_in[3];
    const float* b_enc1   = (const float*)d_in[4];
    const float* W_enc3   = (const float*)d_in[5];
    const float* b_enc3   = (const float*)d_in[6];
    const float* W_dec1   = (const float*)d_in[7];
    const float* b_dec1   = (const float*)d_in[8];
    const float* W_dec3   = (const float*)d_in[9];
    const float* b_dec3   = (const float*)d_in[10];

    const int n = in_sizes[0] / NODELEN;  // 50000
    const int e = in_sizes[1];            // 200000

    // d_out layout: encoded [n,128] | decoded [n,788] | emb [n,788]
    float* encoded = (float*)d_out;
    float* decoded = encoded + (size_t)n * EMBDIM;
    float* emb     = decoded + (size_t)n * IN_DIM;

    // ws layout (bytes); h1 region is reused for bf16 intermediates after gather2
    char* ws = (char*)d_ws;
    unsigned short* h1    = (unsigned short*)(ws + 0);         // n*394*2 = 39.4 MB
    unsigned short* x16   = (unsigned short*)(ws + 0);         // n*192*2 = 19.2 MB
    unsigned short* enc16 = (unsigned short*)(ws + 19200000);  // n*128*2 = 12.8 MB
    unsigned short* y16   = (unsigned short*)(ws + 32000000);  // n*192*2 = 19.2 MB
    unsigned short* Wt1   = (unsigned short*)(ws + 52000000);  // 192*800*2
    unsigned short* Wt2   = (unsigned short*)(ws + 52400000);  // 128*192*2
    unsigned short* Wt3   = (unsigned short*)(ws + 52500000);  // 192*128*2
    unsigned short* Wt4   = (unsigned short*)(ws + 52600000);  // 788*192*2
    float* inv            = (float*)(ws + 53000000);
    int*   deg            = (int*)  (ws + 53200000);
    int*   rowstart       = (int*)  (ws + 53400000);
    int*   cursor         = (int*)  (ws + 53600000);
    int*   elist          = (int*)  (ws + 53800000);           // e*4 = 800 KB
    int*   bsum           = (int*)  (ws + 54600000);

    const int nb = (n + 255) / 256;
    const int eb = (e + 255) / 256;

    // weight transposes (region untouched by h1) — can run up front
    transpose_w<<<(192 * 800 + 255) / 256, 256, 0, stream>>>(W_enc1, Wt1, IN_DIM, H2DIM, 800);
    transpose_w<<<(128 * 192 + 255) / 256, 256, 0, stream>>>(W_enc3, Wt2, H2DIM, EMBDIM, 192);
    transpose_w<<<(192 * 128 + 255) / 256, 256, 0, stream>>>(W_dec1, Wt3, EMBDIM, H2DIM, 128);
    transpose_w<<<(788 * 192 + 255) / 256, 256, 0, stream>>>(W_dec3, Wt4, H2DIM, IN_DIM, 192);

    hipMemsetAsync(deg, 0, (size_t)n * sizeof(int), stream);
    count_deg<<<eb, 256, 0, stream>>>(dst, deg, e);
    block_sum<<<nb, 256, 0, stream>>>(deg, bsum, n);
    scan_bsums<<<1, 256, 0, stream>>>(bsum, nb);
    block_scan<<<nb, 256, 0, stream>>>(deg, bsum, rowstart, cursor, n);
    inv_deg_k<<<nb, 256, 0, stream>>>(deg, inv, n);
    fill_edges<<<eb, 256, 0, stream>>>(src, dst, cursor, elist, e);

    gather1<<<n, 256, 0, stream>>>(features, rowstart, deg, inv, elist, h1);
    gather2_emb<<<n, 256, 0, stream>>>(features, (const unsigned*)h1, rowstart, deg, inv, elist, emb);

    // MLP via bf16 MFMA
    // gemm1: emb(f32)[n,788] @ W1 -> relu -> x16 (bf16). block 64x192 (full N), A read once.
    gemm_mfma<2, 6, 1, 1, 0, 1><<<dim3(782, 1), 256, 0, stream>>>(
        emb, Wt1, b_enc1, nullptr, x16, n, H2DIM, IN_DIM, 25);
    // gemm2: x16 @ W2 -> encoded (f32 out) + enc16 (bf16). block 128x128 (full N).
    gemm_mfma<4, 4, 0, 0, 1, 1><<<dim3(391, 1), 256, 0, stream>>>(
        x16, Wt2, b_enc3, encoded, enc16, n, EMBDIM, H2DIM, 6);
    // gemm3: enc16 @ W3 -> relu -> y16. block 64x192 (full N).
    gemm_mfma<2, 6, 1, 0, 0, 1><<<dim3(782, 1), 256, 0, stream>>>(
        enc16, Wt3, b_dec1, nullptr, y16, n, H2DIM, EMBDIM, 4);
    // gemm4: y16 @ W4 -> decoded (f32). block 128x128, 7 n-blocks.
    gemm_mfma<4, 4, 0, 0, 1, 0><<<dim3(391, 7), 256, 0, stream>>>(
        y16, Wt4, b_dec3, decoded, nullptr, n, IN_DIM, H2DIM, 6);
}